// Round 6
// baseline (303.690 us; speedup 1.0000x reference)
//
#include <hip/hip_runtime.h>
#include <hip/hip_bf16.h>
#include <stdint.h>

#define M_ROWS 8192
#define K_DIM  4096
#define N_DIM  4096

using bf16 = __hip_bfloat16;
typedef __attribute__((ext_vector_type(4))) float f32x4;
typedef __attribute__((ext_vector_type(8))) short s16x8;

__device__ __forceinline__ void gll16(const bf16* g, bf16* l) {
  __builtin_amdgcn_global_load_lds(
      (const __attribute__((address_space(1))) void*)g,
      (__attribute__((address_space(3))) void*)l, 16, 0, 0);
}

// ===========================================================================
// PATH A: A panels LDS-staged (swizzled in global layout), B panels read
// straight to registers (UNSWIZZLED layout).
// A panels: chunk[(tm*64+kt)*2+kh] of 8192 bf16 = [row 256][slot 4][8],
//   data(row,ss) = x[tm*256+row][kt*64+kh*32+(ss^((row>>1)&3))*8..]
// B panels: chunk[(tn*64+kt)*2+kh] = [col 256][slot 4][8] linear:
//   data(col,s)[j] = W[kt*64+kh*32+s*8+j][tn*256+col]
// Fused pre-pass: blocks [0,2048) dequant W -> Bp, blocks [2048,18432) cast
// x -> Ap.
// ===========================================================================
__global__ __launch_bounds__(256) void prep_k(
    const int* __restrict__ qw, const float* __restrict__ s1,
    const float* __restrict__ s2, const float* __restrict__ x,
    bf16* __restrict__ Bp, bf16* __restrict__ Ap)
{
  const int bid = blockIdx.x;
  if (bid < 2048) {
    // ---- dequant (B panels, linear slots) ----
    const int t = bid * 256 + threadIdx.x;   // 0..524287
    const int o = t & 4095;
    const int q = t >> 12;          // 0..127
    const int r0 = q << 2;
    const int g = r0 >> 4;
    const int nt = o >> 8, col = o & 255;
    const int kt = q >> 1, kh = q & 1;
    const float a = s1[g * 4096 + o] * 0.5f;   // codes >= 0 (q>=8)
    const float b = s2[g * 4096 + o] * 0.5f;   // codes <  0
    const uint64_t lo = 0x00FFFEFDFCFAF8F4ull;  // 2*CODE, q=0..7
    const uint64_t hi = 0x0C08060403020100ull;  // 2*CODE, q=8..15
    bf16* dst = Bp + (((size_t)((nt * 64 + kt) * 2 + kh)) << 13) + col * 32;
    #pragma unroll
    for (int j = 0; j < 4; ++j) {
      const uint32_t wbits = (uint32_t)qw[(size_t)(r0 + j) * 4096 + o];
      union { bf16 h[8]; s16x8 v; } u;
      #pragma unroll
      for (int i = 0; i < 8; ++i) {
        const int qc = (wbits >> (4 * i)) & 15;
        const uint64_t pk = (qc & 8) ? hi : lo;
        const int c2 = (int)(int8_t)(uint8_t)(pk >> ((qc & 7) * 8));
        const float sc = (qc & 8) ? a : b;
        u.h[i] = __float2bfloat16((float)c2 * sc);
      }
      *(s16x8*)(dst + (j << 3)) = u.v;
    }
  } else {
    // ---- x cast (A panels, swizzled slots) ----
    const int t = (bid - 2048) * 256 + threadIdx.x;   // 0..4194303
    const int s_lin = t & 3;
    const int kh = (t >> 2) & 1;
    const int kt = (t >> 3) & 63;
    const int m  = t >> 9;
    const int tm = m >> 8, row = m & 255;
    const float* s = x + (size_t)m * 4096 + (kt * 64 + kh * 32 + s_lin * 8);
    f32x4 v0 = *(const f32x4*)s;
    f32x4 v1 = *(const f32x4*)(s + 4);
    union { bf16 h[8]; s16x8 v; } u;
    #pragma unroll
    for (int j = 0; j < 4; ++j) {
      u.h[j]     = __float2bfloat16(v0[j]);
      u.h[4 + j] = __float2bfloat16(v1[j]);
    }
    const int ss = s_lin ^ ((row >> 1) & 3);
    bf16* dst = Ap + (((size_t)((tm * 64 + kt) * 2 + kh)) << 13) + row * 32 + ss * 8;
    *(s16x8*)dst = u.v;
  }
}

// ---------------------------------------------------------------------------
// 256x256 GEMM, BK=64, 8 waves (2Mx4N). A: LDS dbuf (64 KiB, gll-staged,
// max 4 gll outstanding — r3/r4 failed at queue 10, r2/r5 passed at 8;
// stay well under). B: register double-buffer (bb0/bb1), plain coalesced
// loads, compiler-managed waits. One explicit VMW(8) per tile publishes the
// A-glls before the tile-end barrier:
//   entering t: Q=[Bk(t)8]; p0 +A0'(2); p1 +A1'(2); p2 +Bk(t+1)(8);
//   p3 VMW(8) -> clears A0',A1' (oldest glls; in-order), leaves Bk(t+1).
// Slack: A0' 3 phases, A1' 2, Bk 2 — all >= ~500 cy.
// ---------------------------------------------------------------------------
#define BAR()                                                         \
    asm volatile("s_barrier" ::: "memory");                           \
    __builtin_amdgcn_sched_barrier(0)

#define PH_SYNC()                                                     \
    asm volatile("s_barrier" ::: "memory");                           \
    asm volatile("s_waitcnt lgkmcnt(0)" ::: "memory");                \
    __builtin_amdgcn_sched_barrier(0)

#define VMW(N)                                                        \
    asm volatile("s_waitcnt vmcnt(" #N ")" ::: "memory");             \
    __builtin_amdgcn_sched_barrier(0)

#define MFMA16(MH, BO, BARR)                                          \
    __builtin_amdgcn_s_setprio(1);                                    \
    _Pragma("unroll")                                                 \
    for (int m = 0; m < 4; ++m) {                                     \
      _Pragma("unroll")                                               \
      for (int n = 0; n < 4; ++n)                                     \
        acc[(MH)*4+m][n] = __builtin_amdgcn_mfma_f32_16x16x32_bf16(   \
            af[m], BARR[(BO) + n], acc[(MH)*4+m][n], 0, 0, 0);        \
    }                                                                 \
    __builtin_amdgcn_s_setprio(0)

#define KTILE(BUF, TN, PRE, BBC, BBN, WPUB)                           \
  {                                                                   \
    const bf16* A0_ = &lds[BUF][0][0];                                \
    const bf16* A1_ = &lds[BUF][1][0];                                \
    /* p0: (mh0,kk0) */                                               \
    _Pragma("unroll")                                                 \
    for (int m = 0; m < 4; ++m) af[m] = *(const s16x8*)(A0_ + aoff + m * 512); \
    if (PRE) stage(Ab, (TN) * 2, &lds[(BUF)^1][0][0]);                \
    PH_SYNC();                                                        \
    MFMA16(0, 0, BBC);                                                \
    /* p1: (mh1,kk0) */                                               \
    _Pragma("unroll")                                                 \
    for (int m = 0; m < 4; ++m) af[m] = *(const s16x8*)(A0_ + aoff + (m + 4) * 512); \
    if (PRE) stage(Ab, (TN) * 2 + 1, &lds[(BUF)^1][1][0]);            \
    PH_SYNC();                                                        \
    MFMA16(1, 0, BBC);                                                \
    /* p2: (mh0,kk1) */                                               \
    _Pragma("unroll")                                                 \
    for (int m = 0; m < 4; ++m) af[m] = *(const s16x8*)(A1_ + aoff + m * 512); \
    if (PRE) loadB((TN), BBN);                                        \
    PH_SYNC();                                                        \
    MFMA16(0, 4, BBC);                                                \
    /* p3: (mh1,kk1) */                                               \
    _Pragma("unroll")                                                 \
    for (int m = 0; m < 4; ++m) af[m] = *(const s16x8*)(A1_ + aoff + (m + 4) * 512); \
    PH_SYNC();                                                        \
    MFMA16(1, 4, BBC);                                                \
    VMW(WPUB);                                                        \
    BAR();                                                            \
  }

__global__ __launch_bounds__(512, 2) void gemm8_k(
    const bf16* __restrict__ Ap, const bf16* __restrict__ Bp,
    const float* __restrict__ bias, float* __restrict__ out)
{
  __shared__ bf16 lds[2][2][8192];   // A only: [buf][kh][row256*slot4*8]  64 KiB

  const int id  = blockIdx.x;
  const int swz = (id & 7) * 64 + (id >> 3);   // 512 % 8 == 0: bijective
  const int tm  = swz >> 4;      // 0..31
  const int tn  = swz & 15;      // 0..15
  const int tid = (int)threadIdx.x;
  const int lane = tid & 63;
  const int w   = tid >> 6;
  const int wr  = w >> 2;        // 0..1
  const int wc  = w & 3;         // 0..3
  const int lr  = lane & 15;
  const int lg  = lane >> 4;
  const int sl  = (lg ^ ((lr >> 1) & 3)) << 3;      // A swizzled slot (elems)
  const int aoff = (wr * 128 + lr) * 32 + sl;
  const int boffg = (wc * 64 + lr) * 32 + lg * 8;   // B global frag offset

  const bf16* Ab = Ap + ((size_t)tm << 20);
  const bf16* Bb = Bp + ((size_t)tn << 20);

  f32x4 acc[8][4];
  #pragma unroll
  for (int m = 0; m < 8; ++m)
    #pragma unroll
    for (int n = 0; n < 4; ++n) acc[m][n] = (f32x4){0.f, 0.f, 0.f, 0.f};

  auto stage = [&](const bf16* base, int c, bf16* dst) {
    const bf16* s = base + ((size_t)c << 13) + tid * 8;
    gll16(s, dst + tid * 8);
    gll16(s + 4096, dst + tid * 8 + 4096);
  };
  auto loadB = [&](int ktile, s16x8* d) {
    const bf16* base = Bb + (((size_t)ktile * 2) << 13) + boffg;
    #pragma unroll
    for (int kh = 0; kh < 2; ++kh)
      #pragma unroll
      for (int n = 0; n < 4; ++n)
        d[kh * 4 + n] = *(const s16x8*)(base + (kh << 13) + n * 512);
  };

  s16x8 af[4];
  s16x8 bb0[8], bb1[8];

  // prologue: 4 A-glls (order pinned), then 8 B-reg loads; VMW(8) drains glls
  stage(Ab, 0, &lds[0][0][0]);
  stage(Ab, 1, &lds[0][1][0]);
  __builtin_amdgcn_sched_barrier(0);
  loadB(0, bb0);
  VMW(8);
  BAR();

  KTILE(0, 1, 1, bb0, bb1, 8);          // t=0: uses bb0, prefetches tile1
  #pragma unroll 1
  for (int kt2 = 0; kt2 < 31; ++kt2) {
    KTILE(1, (2 * kt2 + 2), 1, bb1, bb0, 8);   // t = 2*kt2+1
    KTILE(0, (2 * kt2 + 3), 1, bb0, bb1, 8);   // t = 2*kt2+2
  }
  KTILE(1, 0, 0, bb1, bb0, 0);          // t=63, drain

  // epilogue: D row=(lane>>4)*4+reg, col=lane&15
  const int orow0 = tm * 256 + wr * 128 + lg * 4;
  const int ocol0 = tn * 256 + wc * 64 + lr;
  float bv[4];
  #pragma unroll
  for (int n = 0; n < 4; ++n) bv[n] = bias[ocol0 + n * 16];
  #pragma unroll
  for (int m = 0; m < 8; ++m) {
    #pragma unroll
    for (int r = 0; r < 4; ++r) {
      float* op = out + (size_t)(orow0 + m * 16 + r) * N_DIM + ocol0;
      #pragma unroll
      for (int n = 0; n < 4; ++n) op[n * 16] = acc[m][n][r] + bv[n];
    }
  }
}

// ===========================================================================
// PATH B fallback (round-1 verified): 128^2 tile, fp32 A reg-staged.
// ===========================================================================
__global__ __launch_bounds__(256) void dequant_f(
    const int* __restrict__ qw, const float* __restrict__ s1,
    const float* __restrict__ s2, bf16* __restrict__ Bp)
{
  const int t = blockIdx.x * 256 + threadIdx.x;
  const int o = t & 4095;
  const int r = t >> 12;
  const int g = r >> 4;
  const int kt = r >> 2;
  const int kk0 = (r & 3) * 8;
  const uint32_t wbits = (uint32_t)qw[(size_t)r * 4096 + o];
  const float a = s1[g * 4096 + o] * 0.5f;
  const float b = s2[g * 4096 + o] * 0.5f;
  const uint64_t lo = 0x00FFFEFDFCFAF8F4ull;
  const uint64_t hi = 0x0C08060403020100ull;
  union { bf16 h[8]; s16x8 v; } u;
  #pragma unroll
  for (int j = 0; j < 8; ++j) {
    const int q = (wbits >> (4 * j)) & 15;
    const uint64_t pk = (q & 8) ? hi : lo;
    const int c2 = (int)(int8_t)(uint8_t)(pk >> ((q & 7) * 8));
    const float s = (q & 8) ? a : b;
    u.h[j] = __float2bfloat16((float)c2 * s);
  }
  const int nt = o >> 7, col = o & 127;
  bf16* dst = Bp + (((size_t)(nt * 128 + kt) * 128 + col) * 32 + kk0);
  *(s16x8*)dst = u.v;
}

__global__ __launch_bounds__(256) void gemmf_k(
    const float* __restrict__ x, const bf16* __restrict__ Bp,
    const float* __restrict__ bias, float* __restrict__ out)
{
  __shared__ bf16 As[2][4096];
  __shared__ bf16 Bs[2][4096];

  const int id  = blockIdx.x;
  const int swz = (id & 7) * 256 + (id >> 3);
  const int tm  = swz >> 5;
  const int tn  = swz & 31;
  const int tid = threadIdx.x;
  const int lane = tid & 63;
  const int w   = tid >> 6;
  const int wr  = (w >> 1) * 64;
  const int wc  = (w & 1) * 64;
  const int lr  = lane & 15;
  const int lg  = lane >> 4;

  f32x4 acc[4][4];
  #pragma unroll
  for (int m = 0; m < 4; ++m)
    #pragma unroll
    for (int n = 0; n < 4; ++n) acc[m][n] = (f32x4){0.f, 0.f, 0.f, 0.f};

  const bf16* bsrc = Bp + ((size_t)tn << 19);
  const float* asrc_f = x + ((size_t)(tm * 128 + (tid >> 1)) << 12) + (tid & 1) * 16;
  float areg[16];

  auto stageB = [&](int kt, int buf) {
    const bf16* bs = bsrc + ((size_t)kt << 12);
    gll16(bs + tid * 8,        &Bs[buf][tid * 8]);
    gll16(bs + 2048 + tid * 8, &Bs[buf][2048 + tid * 8]);
  };
  auto loadA = [&](int kt) {
    const float* s = asrc_f + ((size_t)kt << 5);
    #pragma unroll
    for (int i = 0; i < 4; ++i)
      *(f32x4*)(areg + i * 4) = *(const f32x4*)(s + i * 4);
  };
  auto writeA = [&](int buf) {
    union { bf16 h[16]; s16x8 v[2]; } u;
    #pragma unroll
    for (int i = 0; i < 16; ++i) u.h[i] = __float2bfloat16(areg[i]);
    bf16* d = &As[buf][(tid >> 1) * 32 + (tid & 1) * 16];
    *(s16x8*)d = u.v[0];
    *(s16x8*)(d + 8) = u.v[1];
  };
  auto compute = [&](int buf) {
    s16x8 af[4], bv[4];
    #pragma unroll
    for (int m = 0; m < 4; ++m)
      af[m] = *(const s16x8*)(&As[buf][(wr + m * 16 + lr) * 32 + lg * 8]);
    #pragma unroll
    for (int n = 0; n < 4; ++n)
      bv[n] = *(const s16x8*)(&Bs[buf][(wc + n * 16 + lr) * 32 + lg * 8]);
    #pragma unroll
    for (int m = 0; m < 4; ++m)
      #pragma unroll
      for (int n = 0; n < 4; ++n)
        acc[m][n] = __builtin_amdgcn_mfma_f32_16x16x32_bf16(af[m], bv[n],
                                                            acc[m][n], 0, 0, 0);
  };

  stageB(0, 0);
  loadA(0);
  writeA(0);
  __syncthreads();

  #pragma unroll 2
  for (int kt = 0; kt < 128; ++kt) {
    const int buf = kt & 1;
    if (kt + 1 < 128) {
      stageB(kt + 1, buf ^ 1);
      loadA(kt + 1);
    }
    compute(buf);
    if (kt + 1 < 128) writeA(buf ^ 1);
    __syncthreads();
  }

  const int orow0 = tm * 128 + wr + lg * 4;
  const int ocol0 = tn * 128 + wc + lr;
  float bvv[4];
  #pragma unroll
  for (int n = 0; n < 4; ++n) bvv[n] = bias[ocol0 + n * 16];
  #pragma unroll
  for (int m = 0; m < 4; ++m) {
    #pragma unroll
    for (int r = 0; r < 4; ++r) {
      float* op = out + (size_t)(orow0 + m * 16 + r) * N_DIM + ocol0;
      #pragma unroll
      for (int n = 0; n < 4; ++n)
        op[n * 16] = acc[m][n][r] + bvv[n];
    }
  }
}

extern "C" void kernel_launch(void* const* d_in, const int* in_sizes, int n_in,
                              void* d_out, int out_size, void* d_ws, size_t ws_size,
                              hipStream_t stream) {
  const float* x    = (const float*)d_in[0];
  const int*   qw   = (const int*)d_in[1];
  const float* s1   = (const float*)d_in[2];
  const float* s2   = (const float*)d_in[3];
  const float* bias = (const float*)d_in[4];
  float* out = (float*)d_out;

  const size_t BP_BYTES = (size_t)K_DIM * N_DIM * 2;    // 32 MiB
  const size_t XB_BYTES = (size_t)M_ROWS * K_DIM * 2;   // 64 MiB
  bf16* Bp = (bf16*)d_ws;

  if (ws_size >= BP_BYTES + XB_BYTES) {
    bf16* Ap = (bf16*)((char*)d_ws + BP_BYTES);
    prep_k<<<dim3(18432), dim3(256), 0, stream>>>(qw, s1, s2, x, Bp, Ap);
    gemm8_k<<<dim3(512), dim3(512), 0, stream>>>(Ap, Bp, bias, out);
  } else {
    dequant_f<<<dim3(8192), dim3(256), 0, stream>>>(qw, s1, s2, Bp);
    gemmf_k<<<dim3(2048), dim3(256), 0, stream>>>(x, Bp, bias, out);
  }
}

// Round 7
// 271.007 us; speedup vs baseline: 1.1206x; 1.1206x over previous
//
#include <hip/hip_runtime.h>
#include <hip/hip_bf16.h>
#include <stdint.h>

#define M_ROWS 8192
#define K_DIM  4096
#define N_DIM  4096

using bf16 = __hip_bfloat16;
typedef __attribute__((ext_vector_type(4))) float f32x4;
typedef __attribute__((ext_vector_type(8))) short s16x8;

__device__ __forceinline__ void gll16(const bf16* g, bf16* l) {
  __builtin_amdgcn_global_load_lds(
      (const __attribute__((address_space(1))) void*)g,
      (__attribute__((address_space(3))) void*)l, 16, 0, 0);
}

// ===========================================================================
// PATH A: BK=32 chunks, swizzle baked into global panel layout.
// A panels: chunk[tm*128+kt] (tm=m>>7, kt=k>>5) of 4096 bf16 = [row128][slot4][8]
//   data(row,ss)[j] = x[tm*128+row][kt*32 + (ss^((row>>1)&3))*8 + j]
// B panels: chunk[tn*128+kt] of 8192 bf16 = [col256][slot4][8]
//   data(col,ss)[j] = W[kt*32 + (ss^((col>>1)&3))*8 + j][tn*256+col]
// Fused pre-pass: blocks [0,2048) dequant W -> Bp, [2048,18432) cast x -> Ap.
// ===========================================================================
__global__ __launch_bounds__(256) void prep_k(
    const int* __restrict__ qw, const float* __restrict__ s1,
    const float* __restrict__ s2, const float* __restrict__ x,
    bf16* __restrict__ Bp, bf16* __restrict__ Ap)
{
  const int bid = blockIdx.x;
  if (bid < 2048) {
    // ---- dequant (B panels; identical chunk layout to verified r5) ----
    const int t = bid * 256 + threadIdx.x;   // 0..524287
    const int o = t & 4095;
    const int q = t >> 12;          // kt 0..127
    const int r0 = q << 2;
    const int g = r0 >> 4;
    const int nt = o >> 8, col = o & 255;
    const int sw = (col >> 1) & 3;
    const float a = s1[g * 4096 + o] * 0.5f;   // codes >= 0 (q>=8)
    const float b = s2[g * 4096 + o] * 0.5f;   // codes <  0
    const uint64_t lo = 0x00FFFEFDFCFAF8F4ull;  // 2*CODE, q=0..7
    const uint64_t hi = 0x0C08060403020100ull;  // 2*CODE, q=8..15
    bf16* dst = Bp + (((size_t)(nt * 128 + q)) << 13) + col * 32;
    #pragma unroll
    for (int j = 0; j < 4; ++j) {
      const uint32_t wbits = (uint32_t)qw[(size_t)(r0 + j) * 4096 + o];
      union { bf16 h[8]; s16x8 v; } u;
      #pragma unroll
      for (int i = 0; i < 8; ++i) {
        const int qc = (wbits >> (4 * i)) & 15;
        const uint64_t pk = (qc & 8) ? hi : lo;
        const int c2 = (int)(int8_t)(uint8_t)(pk >> ((qc & 7) * 8));
        const float sc = (qc & 8) ? a : b;
        u.h[i] = __float2bfloat16((float)c2 * sc);
      }
      *(s16x8*)(dst + ((j ^ sw) << 3)) = u.v;
    }
  } else {
    // ---- x cast (A panels, BK=32 chunks) ----
    const int t = (bid - 2048) * 256 + threadIdx.x;   // 0..4194303
    const int k8 = t & 511;          // slot-of-row index: k = k8*8
    const int kt = k8 >> 2;          // 0..127
    const int s_lin = k8 & 3;
    const int m  = t >> 9;
    const int tm = m >> 7, row = m & 127;
    const float* s = x + (size_t)m * 4096 + k8 * 8;
    f32x4 v0 = *(const f32x4*)s;
    f32x4 v1 = *(const f32x4*)(s + 4);
    union { bf16 h[8]; s16x8 v; } u;
    #pragma unroll
    for (int j = 0; j < 4; ++j) {
      u.h[j]     = __float2bfloat16(v0[j]);
      u.h[4 + j] = __float2bfloat16(v1[j]);
    }
    const int ss = s_lin ^ ((row >> 1) & 3);
    bf16* dst = Ap + (((size_t)(tm * 128 + kt)) << 12) + row * 32 + ss * 8;
    *(s16x8*)dst = u.v;
  }
}

// ---------------------------------------------------------------------------
// 128x256 GEMM, BK=32, 8 waves (2Mx4N, 64x64/wave), acc=64 regs,
// __launch_bounds__(512,4) -> <=128 unified regs -> 4 waves/SIMD -> 2
// independent blocks/CU (barrier bubbles of one block filled by the other).
// LDS: 3 bufs x (A 8KiB + B 16KiB) = 72 KiB. One phase per K-tile.
// Ledger (gll units, 3/tile): entering t: {C(t+1)}=3; +C(t+2)->6;
// VMW(3) clears C(t+1); BAR publishes. 2-tile slack, peak 6 (<8).
// WAR: stage at t writes buf[(t+2)%3]=buf[(t-1)%3]; t-1's reads drained at
// t-1's lgkmcnt(0)-in-PH_SYNC, stage issues after t-1's end BAR -> safe.
// ---------------------------------------------------------------------------
#define BAR()                                                         \
    asm volatile("s_barrier" ::: "memory");                           \
    __builtin_amdgcn_sched_barrier(0)

#define PH_SYNC()                                                     \
    asm volatile("s_barrier" ::: "memory");                           \
    asm volatile("s_waitcnt lgkmcnt(0)" ::: "memory");                \
    __builtin_amdgcn_sched_barrier(0)

#define VMW(N)                                                        \
    asm volatile("s_waitcnt vmcnt(" #N ")" ::: "memory");             \
    __builtin_amdgcn_sched_barrier(0)

#define KT9(BUF, KTN, PRE, VM)                                        \
  {                                                                   \
    const bf16* L_ = &lds[BUF][0];                                    \
    _Pragma("unroll")                                                 \
    for (int m = 0; m < 4; ++m) af[m] = *(const s16x8*)(L_ + aoff + m * 512); \
    _Pragma("unroll")                                                 \
    for (int n = 0; n < 4; ++n) bb[n] = *(const s16x8*)(L_ + boff + n * 512); \
    if (PRE) stage((KTN), ((BUF) + 2) % 3);                           \
    PH_SYNC();                                                        \
    __builtin_amdgcn_s_setprio(1);                                    \
    _Pragma("unroll")                                                 \
    for (int m = 0; m < 4; ++m) {                                     \
      _Pragma("unroll")                                               \
      for (int n = 0; n < 4; ++n)                                     \
        acc[m][n] = __builtin_amdgcn_mfma_f32_16x16x32_bf16(          \
            af[m], bb[n], acc[m][n], 0, 0, 0);                        \
    }                                                                 \
    __builtin_amdgcn_s_setprio(0);                                    \
    VMW(VM);                                                          \
    BAR();                                                            \
  }

__global__ __launch_bounds__(512, 4) void gemm9_k(
    const bf16* __restrict__ Ap, const bf16* __restrict__ Bp,
    const float* __restrict__ bias, float* __restrict__ out)
{
  __shared__ bf16 lds[3][12288];   // [buf][A 4096 | B 8192]  72 KiB

  const int id  = blockIdx.x;      // 1024 blocks
  const int xcd = id & 7, lid = id >> 3;
  const int tn  = lid >> 3;                 // 0..15
  const int tm  = xcd * 8 + (lid & 7);      // 0..63  (bijective)
  const int tid = (int)threadIdx.x;
  const int lane = tid & 63;
  const int w   = tid >> 6;
  const int wr  = w >> 2;        // 0..1
  const int wc  = w & 3;         // 0..3
  const int lr  = lane & 15;
  const int lg  = lane >> 4;
  const int sl  = (lg ^ ((lr >> 1) & 3)) << 3;          // swizzled slot
  const int aoff = (wr * 64 + lr) * 32 + sl;
  const int boff = 4096 + (wc * 64 + lr) * 32 + sl;

  const bf16* Abase = Ap + ((size_t)tm << 19);   // tm*128*4096
  const bf16* Bbase = Bp + ((size_t)tn << 20);   // tn*128*8192

  f32x4 acc[4][4];
  #pragma unroll
  for (int m = 0; m < 4; ++m)
    #pragma unroll
    for (int n = 0; n < 4; ++n) acc[m][n] = (f32x4){0.f, 0.f, 0.f, 0.f};

  auto stage = [&](int kt, int buf) {
    gll16(Abase + ((size_t)kt << 12) + tid * 8, &lds[buf][tid * 8]);
    const bf16* bs = Bbase + ((size_t)kt << 13) + tid * 8;
    gll16(bs,        &lds[buf][4096 + tid * 8]);
    gll16(bs + 4096, &lds[buf][8192 + tid * 8]);
  };

  s16x8 af[4], bb[4];

  // prologue: C0 -> buf0, C1 -> buf1 (6 glls); clear C0; publish
  stage(0, 0);
  stage(1, 1);
  VMW(3);
  BAR();

  #pragma unroll 1
  for (int t3 = 0; t3 < 42; ++t3) {
    KT9(0, 3 * t3 + 2, 1, 3);
    KT9(1, 3 * t3 + 3, 1, 3);
    KT9(2, 3 * t3 + 4, 1, 3);
  }
  KT9(0, 0, 0, 0);   // t=126: drain C127
  KT9(1, 0, 0, 0);   // t=127

  // epilogue: D row=(lane>>4)*4+reg, col=lane&15
  const int orow0 = tm * 128 + wr * 64 + lg * 4;
  const int ocol0 = tn * 256 + wc * 64 + lr;
  float bv[4];
  #pragma unroll
  for (int n = 0; n < 4; ++n) bv[n] = bias[ocol0 + n * 16];
  #pragma unroll
  for (int m = 0; m < 4; ++m) {
    #pragma unroll
    for (int r = 0; r < 4; ++r) {
      float* op = out + (size_t)(orow0 + m * 16 + r) * N_DIM + ocol0;
      #pragma unroll
      for (int n = 0; n < 4; ++n) op[n * 16] = acc[m][n][r] + bv[n];
    }
  }
}

// ===========================================================================
// PATH B fallback (round-1 verified): 128^2 tile, fp32 A reg-staged.
// ===========================================================================
__global__ __launch_bounds__(256) void dequant_f(
    const int* __restrict__ qw, const float* __restrict__ s1,
    const float* __restrict__ s2, bf16* __restrict__ Bp)
{
  const int t = blockIdx.x * 256 + threadIdx.x;
  const int o = t & 4095;
  const int r = t >> 12;
  const int g = r >> 4;
  const int kt = r >> 2;
  const int kk0 = (r & 3) * 8;
  const uint32_t wbits = (uint32_t)qw[(size_t)r * 4096 + o];
  const float a = s1[g * 4096 + o] * 0.5f;
  const float b = s2[g * 4096 + o] * 0.5f;
  const uint64_t lo = 0x00FFFEFDFCFAF8F4ull;
  const uint64_t hi = 0x0C08060403020100ull;
  union { bf16 h[8]; s16x8 v; } u;
  #pragma unroll
  for (int j = 0; j < 8; ++j) {
    const int q = (wbits >> (4 * j)) & 15;
    const uint64_t pk = (q & 8) ? hi : lo;
    const int c2 = (int)(int8_t)(uint8_t)(pk >> ((q & 7) * 8));
    const float s = (q & 8) ? a : b;
    u.h[j] = __float2bfloat16((float)c2 * s);
  }
  const int nt = o >> 7, col = o & 127;
  bf16* dst = Bp + (((size_t)(nt * 128 + kt) * 128 + col) * 32 + kk0);
  *(s16x8*)dst = u.v;
}

__global__ __launch_bounds__(256) void gemmf_k(
    const float* __restrict__ x, const bf16* __restrict__ Bp,
    const float* __restrict__ bias, float* __restrict__ out)
{
  __shared__ bf16 As[2][4096];
  __shared__ bf16 Bs[2][4096];

  const int id  = blockIdx.x;
  const int swz = (id & 7) * 256 + (id >> 3);
  const int tm  = swz >> 5;
  const int tn  = swz & 31;
  const int tid = threadIdx.x;
  const int lane = tid & 63;
  const int w   = tid >> 6;
  const int wr  = (w >> 1) * 64;
  const int wc  = (w & 1) * 64;
  const int lr  = lane & 15;
  const int lg  = lane >> 4;

  f32x4 acc[4][4];
  #pragma unroll
  for (int m = 0; m < 4; ++m)
    #pragma unroll
    for (int n = 0; n < 4; ++n) acc[m][n] = (f32x4){0.f, 0.f, 0.f, 0.f};

  const bf16* bsrc = Bp + ((size_t)tn << 19);
  const float* asrc_f = x + ((size_t)(tm * 128 + (tid >> 1)) << 12) + (tid & 1) * 16;
  float areg[16];

  auto stageB = [&](int kt, int buf) {
    const bf16* bs = bsrc + ((size_t)kt << 12);
    gll16(bs + tid * 8,        &Bs[buf][tid * 8]);
    gll16(bs + 2048 + tid * 8, &Bs[buf][2048 + tid * 8]);
  };
  auto loadA = [&](int kt) {
    const float* s = asrc_f + ((size_t)kt << 5);
    #pragma unroll
    for (int i = 0; i < 4; ++i)
      *(f32x4*)(areg + i * 4) = *(const f32x4*)(s + i * 4);
  };
  auto writeA = [&](int buf) {
    union { bf16 h[16]; s16x8 v[2]; } u;
    #pragma unroll
    for (int i = 0; i < 16; ++i) u.h[i] = __float2bfloat16(areg[i]);
    bf16* d = &As[buf][(tid >> 1) * 32 + (tid & 1) * 16];
    *(s16x8*)d = u.v[0];
    *(s16x8*)(d + 8) = u.v[1];
  };
  auto compute = [&](int buf) {
    s16x8 af[4], bv[4];
    #pragma unroll
    for (int m = 0; m < 4; ++m)
      af[m] = *(const s16x8*)(&As[buf][(wr + m * 16 + lr) * 32 + lg * 8]);
    #pragma unroll
    for (int n = 0; n < 4; ++n)
      bv[n] = *(const s16x8*)(&Bs[buf][(wc + n * 16 + lr) * 32 + lg * 8]);
    #pragma unroll
    for (int m = 0; m < 4; ++m)
      #pragma unroll
      for (int n = 0; n < 4; ++n)
        acc[m][n] = __builtin_amdgcn_mfma_f32_16x16x32_bf16(af[m], bv[n],
                                                            acc[m][n], 0, 0, 0);
  };

  stageB(0, 0);
  loadA(0);
  writeA(0);
  __syncthreads();

  #pragma unroll 2
  for (int kt = 0; kt < 128; ++kt) {
    const int buf = kt & 1;
    if (kt + 1 < 128) {
      stageB(kt + 1, buf ^ 1);
      loadA(kt + 1);
    }
    compute(buf);
    if (kt + 1 < 128) writeA(buf ^ 1);
    __syncthreads();
  }

  const int orow0 = tm * 128 + wr + lg * 4;
  const int ocol0 = tn * 128 + wc + lr;
  float bvv[4];
  #pragma unroll
  for (int n = 0; n < 4; ++n) bvv[n] = bias[ocol0 + n * 16];
  #pragma unroll
  for (int m = 0; m < 4; ++m) {
    #pragma unroll
    for (int r = 0; r < 4; ++r) {
      float* op = out + (size_t)(orow0 + m * 16 + r) * N_DIM + ocol0;
      #pragma unroll
      for (int n = 0; n < 4; ++n)
        op[n * 16] = acc[m][n][r] + bvv[n];
    }
  }
}

extern "C" void kernel_launch(void* const* d_in, const int* in_sizes, int n_in,
                              void* d_out, int out_size, void* d_ws, size_t ws_size,
                              hipStream_t stream) {
  const float* x    = (const float*)d_in[0];
  const int*   qw   = (const int*)d_in[1];
  const float* s1   = (const float*)d_in[2];
  const float* s2   = (const float*)d_in[3];
  const float* bias = (const float*)d_in[4];
  float* out = (float*)d_out;

  const size_t BP_BYTES = (size_t)K_DIM * N_DIM * 2;    // 32 MiB
  const size_t XB_BYTES = (size_t)M_ROWS * K_DIM * 2;   // 64 MiB
  bf16* Bp = (bf16*)d_ws;

  if (ws_size >= BP_BYTES + XB_BYTES) {
    bf16* Ap = (bf16*)((char*)d_ws + BP_BYTES);
    prep_k<<<dim3(18432), dim3(256), 0, stream>>>(qw, s1, s2, x, Bp, Ap);
    gemm9_k<<<dim3(1024), dim3(512), 0, stream>>>(Ap, Bp, bias, out);
  } else {
    dequant_f<<<dim3(8192), dim3(256), 0, stream>>>(qw, s1, s2, Bp);
    gemmf_k<<<dim3(2048), dim3(256), 0, stream>>>(x, Bp, bias, out);
  }
}